// Round 13
// baseline (191.524 us; speedup 1.0000x reference)
//
#include <hip/hip_runtime.h>
#include <cstdint>
#include <cstddef>

#define TPB 256
static constexpr float RSQRT_C_F = 0.35355339059327373f;  // 1/sqrt(8)

typedef __attribute__((ext_vector_type(8))) short bf16x8;
typedef __attribute__((ext_vector_type(4))) float f32x4;

__device__ __forceinline__ unsigned short f2bf(float f) {
    unsigned u = __float_as_uint(f);
    u += 0x7FFFu + ((u >> 16) & 1u);          // round-to-nearest-even
    return (unsigned short)(u >> 16);
}
__device__ __forceinline__ float bf2f(unsigned short h) {
    return __uint_as_float((unsigned)h << 16);
}
// lo element exact (shift); hi element keeps garbage low mantissa bits
// (<=2^-8 relative perturbation -- same order as bf16 rounding; exponent safe)
__device__ __forceinline__ float loF(unsigned u) { return __uint_as_float(u << 16); }
__device__ __forceinline__ float hiF(unsigned u) { return __uint_as_float(u); }

// ---------------------------------------------------------------------------
// prep1 (gridded): build Wbig [64][320] = [ Wq | Wk@BD(Watt0)*prior0*rsqrtC |
//   Wk@BD(Watt1)*prior1*rsqrtC | Wm@BD(Wmsg0) | Wm@BD(Wmsg1) ] and bbig[320].
// ---------------------------------------------------------------------------
__global__ void prep1_kernel(const float* __restrict__ Wq, const float* __restrict__ bq,
                             const float* __restrict__ Wk, const float* __restrict__ bk,
                             const float* __restrict__ Wm, const float* __restrict__ bm,
                             const float* __restrict__ Watt0, const float* __restrict__ prior0,
                             const float* __restrict__ Watt1, const float* __restrict__ prior1,
                             const float* __restrict__ Wmsg0, const float* __restrict__ Wmsg1,
                             float* __restrict__ Wbig, float* __restrict__ bbig) {
    int idx = blockIdx.x * TPB + threadIdx.x;
    if (idx < 64 * 320) {
        int i = idx / 320, col = idx % 320;
        float v;
        if (col < 64) {
            v = Wq[i * 64 + col];
        } else {
            int j = col - 64, set = j >> 6, l = j & 63, h = l >> 3, lc = l & 7;
            const float* Win = (set < 2) ? Wk : Wm;
            const float* T = (set == 0) ? Watt0 : (set == 1) ? Watt1 : (set == 2) ? Wmsg0 : Wmsg1;
            float scale = (set == 0) ? prior0[h] * RSQRT_C_F
                        : (set == 1) ? prior1[h] * RSQRT_C_F : 1.f;
            float acc = 0.f;
            #pragma unroll
            for (int c = 0; c < 8; c++) acc += Win[i * 64 + h * 8 + c] * T[h * 64 + c * 8 + lc];
            v = acc * scale;
        }
        Wbig[idx] = v;
    } else if (idx < 64 * 320 + 320) {
        int col = idx - 64 * 320;
        float v;
        if (col < 64) {
            v = bq[col];
        } else {
            int j = col - 64, set = j >> 6, l = j & 63, h = l >> 3, lc = l & 7;
            const float* bin = (set < 2) ? bk : bm;
            const float* T = (set == 0) ? Watt0 : (set == 1) ? Watt1 : (set == 2) ? Wmsg0 : Wmsg1;
            float scale = (set == 0) ? prior0[h] * RSQRT_C_F
                        : (set == 1) ? prior1[h] * RSQRT_C_F : 1.f;
            float acc = 0.f;
            #pragma unroll
            for (int c = 0; c < 8; c++) acc += bin[h * 8 + c] * T[h * 64 + c * 8 + lc];
            v = acc * scale;
        }
        bbig[col] = v;
    }
}

// ---------------------------------------------------------------------------
// prep2 (gridded): pack Wbig -> Wpack (40 frags) and Wa -> Wapack (8 frags).
// ---------------------------------------------------------------------------
__global__ void prep2_kernel(const float* __restrict__ Wbig, const float* __restrict__ Wa,
                             unsigned short* __restrict__ Wpack,
                             unsigned short* __restrict__ Wapack) {
    int p = blockIdx.x * TPB + threadIdx.x;
    bool isWa = (p >= 40 * 64);
    if (p >= 48 * 64) return;
    int pl = isWa ? p - 40 * 64 : p;
    int lane = pl & 63, ctkt = pl >> 6;
    int ct = ctkt >> 1, kt = ctkt & 1;
    int kbase = kt * 32 + (lane >> 4) * 8;
    int col = ct * 16 + (lane & 15);
    const float* W = isWa ? Wa : Wbig;
    const int stride = isWa ? 64 : 320;
    unsigned short h[8];
    #pragma unroll
    for (int j = 0; j < 8; j++) h[j] = f2bf(W[(size_t)(kbase + j) * stride + col]);
    uint4 pk;
    pk.x = (unsigned)h[0] | ((unsigned)h[1] << 16);
    pk.y = (unsigned)h[2] | ((unsigned)h[3] << 16);
    pk.z = (unsigned)h[4] | ((unsigned)h[5] << 16);
    pk.w = (unsigned)h[6] | ((unsigned)h[7] << 16);
    unsigned short* dst = isWa ? Wapack : Wpack;
    *(uint4*)&dst[(size_t)pl * 8] = pk;
}

// ---------------------------------------------------------------------------
// FUSED proj + hist: blocks [0, projBlocks) run MFMA projection; blocks
// [projBlocks, ...) run the dst histogram (independent work, overlapped).
// kmbuf layout (bf16): node*256 + set*128 + j*16 + {k:0..7 | m:8..15}
//   -> one edge's 8 lanes read ONE 256B contiguous burst.
// hist sub-bucket: b&7 == (e>>8)&7 (TPB=256), matching scatter_kernel.
// ---------------------------------------------------------------------------
__global__ __launch_bounds__(TPB) void proj_hist(const float* __restrict__ x,
                                                 const unsigned short* __restrict__ Wpack,
                                                 const float* __restrict__ bbig,
                                                 unsigned short* __restrict__ qbuf,
                                                 unsigned short* __restrict__ kmbuf,
                                                 int N, int projBlocks,
                                                 const int* __restrict__ dst0,
                                                 const int* __restrict__ dst1,
                                                 int* __restrict__ sub,
                                                 int* __restrict__ rank,
                                                 int E0, int Etot) {
    if (blockIdx.x >= (unsigned)projBlocks) {
        // ---- hist part ----
        int b = blockIdx.x - projBlocks;
        int e = b * TPB + threadIdx.x;
        if (e >= Etot) return;
        int d = (e < E0) ? dst0[e] : dst1[e - E0];
        d = min(max(d, 0), N - 1);
        rank[e] = atomicAdd(&sub[(b & 7) * N + d], 1);
        return;
    }
    // ---- proj part ----
    const int lane = threadIdx.x & 63;
    const int wv = threadIdx.x >> 6;
    const int rowbase = blockIdx.x * 64 + wv * 16;
    const int arow = min(rowbase + (lane & 15), N - 1);
    const int kbase = (lane >> 4) * 8;

    bf16x8 afrag[2];
    #pragma unroll
    for (int kt = 0; kt < 2; kt++) {
        const float* xp = x + (size_t)arow * 64 + kt * 32 + kbase;
        float4 v0 = *(const float4*)xp;
        float4 v1 = *(const float4*)(xp + 4);
        bf16x8 a;
        a[0] = (short)f2bf(v0.x); a[1] = (short)f2bf(v0.y);
        a[2] = (short)f2bf(v0.z); a[3] = (short)f2bf(v0.w);
        a[4] = (short)f2bf(v1.x); a[5] = (short)f2bf(v1.y);
        a[6] = (short)f2bf(v1.z); a[7] = (short)f2bf(v1.w);
        afrag[kt] = a;
    }

    const int colq = lane & 15;
    const int rgrp = (lane >> 4) * 4;

    for (int ct = 0; ct < 20; ct++) {
        bf16x8 b0 = *(const bf16x8*)(Wpack + ((size_t)(ct * 2 + 0) * 64 + lane) * 8);
        bf16x8 b1 = *(const bf16x8*)(Wpack + ((size_t)(ct * 2 + 1) * 64 + lane) * 8);
        f32x4 acc = {0.f, 0.f, 0.f, 0.f};
        acc = __builtin_amdgcn_mfma_f32_16x16x32_bf16(afrag[0], b0, acc, 0, 0, 0);
        acc = __builtin_amdgcn_mfma_f32_16x16x32_bf16(afrag[1], b1, acc, 0, 0, 0);
        const int col = ct * 16 + colq;
        const float bv = bbig[col];
        if (ct < 4) {
            #pragma unroll
            for (int r = 0; r < 4; r++) {
                int row = rowbase + rgrp + r;
                if (row < N) qbuf[(size_t)row * 64 + col] = f2bf(acc[r] + bv);
            }
        } else {
            // Wbig col groups: k0(64-127) k1(128-191) m0(192-255) m1(256-319)
            const int cm = col - 64;
            const int g = cm >> 6;              // 0:k0 1:k1 2:m0 3:m1
            const int w = cm & 63;
            const int h = w >> 3, c = w & 7;
            const int set = g & 1, ism = g >> 1;
            const int addr = set * 128 + h * 16 + ism * 8 + c;
            #pragma unroll
            for (int r = 0; r < 4; r++) {
                int row = rowbase + rgrp + r;
                if (row < N) kmbuf[(size_t)row * 256 + addr] = f2bf(acc[r] + bv);
            }
        }
    }
}

// ---- scan over counts (sumsub FUSED in): also writes sub exclusive bases ----
__global__ void scan1(int* __restrict__ sub, int* __restrict__ offsets,
                      int* __restrict__ blocksums, int n) {
    __shared__ int sums[TPB];
    int b = blockIdx.x, t = threadIdx.x;
    int base = b * 1024 + t * 4;
    int cnt[4];
    #pragma unroll
    for (int i = 0; i < 4; i++) {
        int d = base + i;
        int s = 0;
        if (d < n) {
            #pragma unroll
            for (int bb = 0; bb < 8; bb++) {
                int v = sub[bb * n + d];
                sub[bb * n + d] = s;     // exclusive prefix base
                s += v;
            }
        }
        cnt[i] = s;
    }
    int local = cnt[0] + cnt[1] + cnt[2] + cnt[3];
    sums[t] = local;
    __syncthreads();
    for (int off = 1; off < TPB; off <<= 1) {
        int add = (t >= off) ? sums[t - off] : 0;
        __syncthreads();
        sums[t] += add;
        __syncthreads();
    }
    int excl = sums[t] - local;
    if (base + 0 < n) offsets[base + 0] = excl;
    if (base + 1 < n) offsets[base + 1] = excl + cnt[0];
    if (base + 2 < n) offsets[base + 2] = excl + cnt[0] + cnt[1];
    if (base + 3 < n) offsets[base + 3] = excl + cnt[0] + cnt[1] + cnt[2];
    if (t == TPB - 1) blocksums[b] = sums[TPB - 1];
}

__global__ void scan2(int* __restrict__ blocksums, int nb) {  // nb <= 256
    __shared__ int s[TPB];
    int t = threadIdx.x;
    int v = (t < nb) ? blocksums[t] : 0;
    s[t] = v;
    __syncthreads();
    for (int off = 1; off < TPB; off <<= 1) {
        int add = (t >= off) ? s[t - off] : 0;
        __syncthreads();
        s[t] += add;
        __syncthreads();
    }
    if (t < nb) blocksums[t] = s[t] - v;  // exclusive
}

// scan3 + fused addoff: finalize offsets AND fold them into the 8 sub bases
__global__ void scan3(int* __restrict__ offsets, const int* __restrict__ blocksums,
                      int* __restrict__ sub, int n, int Etot) {
    int i = blockIdx.x * TPB + threadIdx.x;
    if (i < n) {
        int v = offsets[i] + blocksums[i >> 10];
        offsets[i] = v;
        #pragma unroll
        for (int b = 0; b < 8; b++) sub[b * n + i] += v;
    }
    if (i == n) offsets[n] = Etot;
}

// scatter WITHOUT atomics: pos = sub_abs[(e>>8)&7][d] + rank[e]
__global__ void scatter_kernel(const int* __restrict__ src0, const int* __restrict__ dst0,
                               const int* __restrict__ src1, const int* __restrict__ dst1,
                               const int* __restrict__ sub,
                               const int* __restrict__ rank, unsigned* __restrict__ records,
                               int E0, int Etot, int N) {
    int e = blockIdx.x * TPB + threadIdx.x;
    if (e >= Etot) return;
    int s, d, setbit;
    if (e < E0) { s = src0[e]; d = dst0[e]; setbit = 0; }
    else        { s = src1[e - E0]; d = dst1[e - E0]; setbit = 1; }
    d = min(max(d, 0), N - 1);
    int sb = (e >> 8) & 7;   // must match hist's (b & 7) with TPB=256
    int pos = sub[sb * N + d] + rank[e];
    pos = min(max(pos, 0), Etot - 1);
    records[pos] = (unsigned)s | ((unsigned)setbit << 24);
}

// ---------------------------------------------------------------------------
// Pool v5: one 8-lane group per receiver (wave = 8 receivers).
// lane = (g, j): g = lane>>3 receiver slot, j = lane&7 head.
// Interleaved kmbuf: k and m for (node,set,j) are 32B ADJACENT; one edge's
// 8 lanes read a single 256B contiguous burst. Zero shuffles, zero reduce.
// No online max (scores O(0.1) by construction; fminf(s,60) guards; softmax
// shift-invariance => matches reference). Unroll x2 for load ILP.
// ---------------------------------------------------------------------------
__global__ __launch_bounds__(TPB) void pool_kernel(const unsigned short* __restrict__ qbuf,
                                                   const unsigned short* __restrict__ kmbuf,
                                                   const unsigned* __restrict__ records,
                                                   const int* __restrict__ offsets,
                                                   unsigned short* __restrict__ pooledN,
                                                   int N) {
    const int lane = threadIdx.x & 63;
    const int j = lane & 7;
    const int r = ((blockIdx.x * TPB + threadIdx.x) >> 6) * 8 + (lane >> 3);
    if (r >= N) return;
    const int beg = offsets[r], end = offsets[r + 1];

    uint4 qv = *(const uint4*)(qbuf + (size_t)r * 64 + (j << 3));
    float qa0 = loF(qv.x), qa1 = hiF(qv.x), qa2 = loF(qv.y), qa3 = hiF(qv.y);
    float qa4 = loF(qv.z), qa5 = hiF(qv.z), qa6 = loF(qv.w), qa7 = hiF(qv.w);

    float d_run = 0.f;
    float p0 = 0.f, p1 = 0.f, p2 = 0.f, p3 = 0.f, p4 = 0.f, p5 = 0.f, p6 = 0.f, p7 = 0.f;

#define EDGE(T) {                                                              \
        unsigned rec = records[T];                                             \
        size_t base = ((size_t)(rec & 0xFFFFFFu) << 8) + (((rec >> 24) & 1u) << 7) + (j << 4); \
        uint4 kv = *(const uint4*)(kmbuf + base);                              \
        uint4 mv = *(const uint4*)(kmbuf + base + 8);                          \
        float s = loF(kv.x) * qa0 + hiF(kv.x) * qa1                            \
                + loF(kv.y) * qa2 + hiF(kv.y) * qa3                            \
                + loF(kv.z) * qa4 + hiF(kv.z) * qa5                            \
                + loF(kv.w) * qa6 + hiF(kv.w) * qa7;                           \
        float c = __expf(fminf(s, 60.f));                                      \
        d_run += c;                                                            \
        p0 += c * loF(mv.x); p1 += c * hiF(mv.x);                              \
        p2 += c * loF(mv.y); p3 += c * hiF(mv.y);                              \
        p4 += c * loF(mv.z); p5 += c * hiF(mv.z);                              \
        p6 += c * loF(mv.w); p7 += c * hiF(mv.w);                              \
    }

    int t = beg;
    for (; t + 1 < end; t += 2) { EDGE(t); EDGE(t + 1); }
    if (t < end) EDGE(t);
#undef EDGE

    const float inv = (end > beg) ? 1.f / d_run : 0.f;
    uint4 ov;
    ov.x = (unsigned)f2bf(p0 * inv) | ((unsigned)f2bf(p1 * inv) << 16);
    ov.y = (unsigned)f2bf(p2 * inv) | ((unsigned)f2bf(p3 * inv) << 16);
    ov.z = (unsigned)f2bf(p4 * inv) | ((unsigned)f2bf(p5 * inv) << 16);
    ov.w = (unsigned)f2bf(p6 * inv) | ((unsigned)f2bf(p7 * inv) << 16);
    *(uint4*)(pooledN + (size_t)r * 64 + (j << 3)) = ov;
}

// ---------------------------------------------------------------------------
// MFMA final: out = LN( sc*(gelu(pooledN) @ Wa + ba) + (1-sc)*x ).
// ---------------------------------------------------------------------------
__global__ __launch_bounds__(TPB) void final_mfma(const float* __restrict__ x,
                                                  const unsigned short* __restrict__ pooledN,
                                                  const unsigned short* __restrict__ Wapack,
                                                  const float* __restrict__ ba,
                                                  const float* __restrict__ skipw,
                                                  const float* __restrict__ gamma,
                                                  const float* __restrict__ beta,
                                                  float* __restrict__ out, int N) {
    const int lane = threadIdx.x & 63;
    const int wv = threadIdx.x >> 6;
    const int rowbase = blockIdx.x * 64 + wv * 16;
    const int arow = min(rowbase + (lane & 15), N - 1);
    const int kbase = (lane >> 4) * 8;
    const float sc = 1.f / (1.f + __expf(-skipw[0]));

    bf16x8 afrag[2];
    #pragma unroll
    for (int kt = 0; kt < 2; kt++) {
        uint4 pv = *(const uint4*)(pooledN + (size_t)arow * 64 + kt * 32 + kbase);
        float g[8];
        g[0] = loF(pv.x); g[1] = bf2f((unsigned short)(pv.x >> 16));
        g[2] = loF(pv.y); g[3] = bf2f((unsigned short)(pv.y >> 16));
        g[4] = loF(pv.z); g[5] = bf2f((unsigned short)(pv.z >> 16));
        g[6] = loF(pv.w); g[7] = bf2f((unsigned short)(pv.w >> 16));
        bf16x8 a;
        #pragma unroll
        for (int i = 0; i < 8; i++) {
            float gg = 0.5f * g[i] * (1.f + erff(g[i] * 0.70710678118654752f));
            a[i] = (short)f2bf(gg);
        }
        afrag[kt] = a;
    }

    const int colq = lane & 15;
    const int rgrp = (lane >> 4) * 4;

    float o[4][4];   // [ct][r] post-skip values
    #pragma unroll
    for (int ct = 0; ct < 4; ct++) {
        bf16x8 b0 = *(const bf16x8*)(Wapack + ((size_t)(ct * 2 + 0) * 64 + lane) * 8);
        bf16x8 b1 = *(const bf16x8*)(Wapack + ((size_t)(ct * 2 + 1) * 64 + lane) * 8);
        f32x4 acc = {0.f, 0.f, 0.f, 0.f};
        acc = __builtin_amdgcn_mfma_f32_16x16x32_bf16(afrag[0], b0, acc, 0, 0, 0);
        acc = __builtin_amdgcn_mfma_f32_16x16x32_bf16(afrag[1], b1, acc, 0, 0, 0);
        const int col = ct * 16 + colq;
        const float bav = ba[col];
        #pragma unroll
        for (int r = 0; r < 4; r++) {
            int row = min(rowbase + rgrp + r, N - 1);
            float xv = x[(size_t)row * 64 + col];
            o[ct][r] = sc * (acc[r] + bav) + (1.f - sc) * xv;
        }
    }

    #pragma unroll
    for (int r = 0; r < 4; r++) {
        float s1 = o[0][r] + o[1][r] + o[2][r] + o[3][r];
        float s2 = o[0][r] * o[0][r] + o[1][r] * o[1][r]
                 + o[2][r] * o[2][r] + o[3][r] * o[3][r];
        #pragma unroll
        for (int off = 1; off <= 8; off <<= 1) {
            s1 += __shfl_xor(s1, off, 64);
            s2 += __shfl_xor(s2, off, 64);
        }
        float mu = s1 * (1.f / 64.f);
        float var = s2 * (1.f / 64.f) - mu * mu;
        float rs = rsqrtf(var + 1e-3f);
        const int row = rowbase + rgrp + r;
        if (row < N) {
            #pragma unroll
            for (int ct = 0; ct < 4; ct++) {
                const int col = ct * 16 + colq;
                out[(size_t)row * 64 + col] = gamma[col] * (o[ct][r] - mu) * rs + beta[col];
            }
        }
    }
}

extern "C" void kernel_launch(void* const* d_in, const int* in_sizes, int n_in,
                              void* d_out, int out_size, void* d_ws, size_t ws_size,
                              hipStream_t stream) {
    const float* x      = (const float*)d_in[0];
    const int*   src0   = (const int*)d_in[1];
    const int*   dst0   = (const int*)d_in[2];
    const int*   src1   = (const int*)d_in[3];
    const int*   dst1   = (const int*)d_in[4];
    const float* Wk     = (const float*)d_in[5];
    const float* bk     = (const float*)d_in[6];
    const float* Wm     = (const float*)d_in[7];
    const float* bm     = (const float*)d_in[8];
    const float* Wq     = (const float*)d_in[9];
    const float* bq     = (const float*)d_in[10];
    const float* Wa     = (const float*)d_in[11];
    const float* ba     = (const float*)d_in[12];
    const float* Watt0  = (const float*)d_in[13];
    const float* Wmsg0  = (const float*)d_in[14];
    const float* prior0 = (const float*)d_in[15];
    const float* Watt1  = (const float*)d_in[16];
    const float* Wmsg1  = (const float*)d_in[17];
    const float* prior1 = (const float*)d_in[18];
    const float* skipw  = (const float*)d_in[19];
    const float* gamma  = (const float*)d_in[20];
    const float* beta   = (const float*)d_in[21];

    const int N  = in_sizes[0] / 64;
    const int E0 = in_sizes[1];
    const int E1 = in_sizes[3];
    const int Etot = E0 + E1;

    // workspace layout
    float* ws       = (float*)d_ws;
    float* Wbig     = ws;                                   // 64*320 f32
    float* bbig     = Wbig + 64 * 320;                      // 320 f32
    unsigned short* Wpack  = (unsigned short*)(bbig + 320); // 40*64*8 bf16 (40 KB)
    unsigned short* Wapack = Wpack + 40 * 64 * 8;           // 8*64*8 bf16 (8 KB)
    unsigned short* qbuf   = Wapack + 8 * 64 * 8;           // N*64 bf16
    unsigned short* pooledN = qbuf + (size_t)N * 64;        // N*64 bf16
    unsigned short* kmbuf  = pooledN + (size_t)N * 64;      // N*256 bf16 (interleaved k|m)
    int* sub        = (int*)(kmbuf + (size_t)N * 256);      // 8*N (counts -> abs bases)
    int* offsets    = sub + (size_t)8 * N;                  // N+1
    int* blocksums  = offsets + N + 1;                      // <=512
    int* rank       = blocksums + 512;                      // Etot
    unsigned* records = (unsigned*)(rank + Etot);           // Etot

    const int nb1 = (N + 1023) / 1024;
    const int gE = (Etot + TPB - 1) / TPB;
    const int projBlocks = (N + 63) / 64;

    prep1_kernel<<<(64 * 320 + 320 + TPB - 1) / TPB, TPB, 0, stream>>>(
        Wq, bq, Wk, bk, Wm, bm, Watt0, prior0, Watt1, prior1, Wmsg0, Wmsg1, Wbig, bbig);
    hipMemsetAsync(sub, 0, (size_t)8 * N * sizeof(int), stream);
    prep2_kernel<<<(48 * 64 + TPB - 1) / TPB, TPB, 0, stream>>>(Wbig, Wa, Wpack, Wapack);

    proj_hist<<<projBlocks + gE, TPB, 0, stream>>>(x, Wpack, bbig, qbuf, kmbuf, N,
                                                   projBlocks, dst0, dst1, sub, rank,
                                                   E0, Etot);

    scan1<<<nb1, TPB, 0, stream>>>(sub, offsets, blocksums, N);
    scan2<<<1, TPB, 0, stream>>>(blocksums, nb1);
    scan3<<<(N + 1 + TPB - 1) / TPB, TPB, 0, stream>>>(offsets, blocksums, sub, N, Etot);

    scatter_kernel<<<gE, TPB, 0, stream>>>(src0, dst0, src1, dst1, sub,
                                           rank, records, E0, Etot, N);

    pool_kernel<<<((size_t)N * 8 + TPB - 1) / TPB, TPB, 0, stream>>>(qbuf, kmbuf, records,
                                                                     offsets, pooledN, N);

    final_mfma<<<(N + 63) / 64, TPB, 0, stream>>>(x, pooledN, Wapack, ba, skipw,
                                                  gamma, beta, (float*)d_out, N);
}

// Round 14
// 161.312 us; speedup vs baseline: 1.1873x; 1.1873x over previous
//
#include <hip/hip_runtime.h>
#include <hip/hip_fp16.h>
#include <cstdint>
#include <cstddef>

#define TPB 256
static constexpr float RSQRT_C_F = 0.35355339059327373f;  // 1/sqrt(8)

typedef __attribute__((ext_vector_type(8))) short bf16x8;
typedef __attribute__((ext_vector_type(4))) float f32x4;
typedef __attribute__((ext_vector_type(2))) float f32x2;

#if __has_builtin(__builtin_amdgcn_cvt_pk_f32_fp8) && __has_builtin(__builtin_amdgcn_cvt_pk_fp8_f32)
#define USE_HW_FP8 1
#endif

__device__ __forceinline__ unsigned short f2bf(float f) {
    unsigned u = __float_as_uint(f);
    u += 0x7FFFu + ((u >> 16) & 1u);          // round-to-nearest-even
    return (unsigned short)(u >> 16);
}
__device__ __forceinline__ float bf2f(unsigned short h) {
    return __uint_as_float((unsigned)h << 16);
}
__device__ __forceinline__ float loF(unsigned u) { return __uint_as_float(u << 16); }
__device__ __forceinline__ float hiF(unsigned u) { return __uint_as_float(u); }

// ---- fp8 e4m3 encode/decode (HW path via v_cvt_*, SW fallback) ----
__device__ __forceinline__ unsigned char enc8(float v) {
#ifdef USE_HW_FP8
    return (unsigned char)(__builtin_amdgcn_cvt_pk_fp8_f32(v, v, 0, false) & 0xff);
#else
    unsigned s = (__float_as_uint(v) >> 24) & 0x80u;
    float a = fabsf(v);
    if (a < 0.015625f) {                        // subnormal region (< 2^-6)
        int m = __float2int_rn(a * 512.f);      // 0..8 (8 -> 0x08 == 2^-6)
        return (unsigned char)(s | (unsigned)m);
    }
    if (a > 448.f) return (unsigned char)(s | 0x7e);
    unsigned u = __float_as_uint(a);
    u += 0x7FFFFu + ((u >> 20) & 1u);           // RNE into bit 20
    unsigned e8 = ((u >> 23) & 0xffu) - 120u;
    unsigned m3 = (u >> 20) & 7u;
    if (e8 > 15u) return (unsigned char)(s | 0x7e);
    return (unsigned char)(s | (e8 << 3) | m3);
#endif
}

__device__ __forceinline__ void dec8x8(uint2 v, float* o) {
#ifdef USE_HW_FP8
    f32x2 a = __builtin_amdgcn_cvt_pk_f32_fp8((int)v.x, false);
    f32x2 b = __builtin_amdgcn_cvt_pk_f32_fp8((int)v.x, true);
    f32x2 c = __builtin_amdgcn_cvt_pk_f32_fp8((int)v.y, false);
    f32x2 d = __builtin_amdgcn_cvt_pk_f32_fp8((int)v.y, true);
    o[0] = a.x; o[1] = a.y; o[2] = b.x; o[3] = b.y;
    o[4] = c.x; o[5] = c.y; o[6] = d.x; o[7] = d.y;
#else
    unsigned w[2] = {v.x, v.y};
    #pragma unroll
    for (int i = 0; i < 8; i++) {
        unsigned bb = (w[i >> 2] >> ((i & 3) * 8)) & 0xffu;
        unsigned short hs = (unsigned short)(((bb & 0x80u) << 8) | ((bb & 0x7fu) << 7));
        __half h = *reinterpret_cast<__half*>(&hs);   // e4m3 bits in f16 slot => val/256
        o[i] = 256.f * __half2float(h);
    }
#endif
}

// ---------------------------------------------------------------------------
// prep1 (gridded): build Wbig [64][320] = [ Wq | Wk@BD(Watt0)*prior0*rsqrtC |
//   Wk@BD(Watt1)*prior1*rsqrtC | Wm@BD(Wmsg0) | Wm@BD(Wmsg1) ] and bbig[320].
// ---------------------------------------------------------------------------
__global__ void prep1_kernel(const float* __restrict__ Wq, const float* __restrict__ bq,
                             const float* __restrict__ Wk, const float* __restrict__ bk,
                             const float* __restrict__ Wm, const float* __restrict__ bm,
                             const float* __restrict__ Watt0, const float* __restrict__ prior0,
                             const float* __restrict__ Watt1, const float* __restrict__ prior1,
                             const float* __restrict__ Wmsg0, const float* __restrict__ Wmsg1,
                             float* __restrict__ Wbig, float* __restrict__ bbig) {
    int idx = blockIdx.x * TPB + threadIdx.x;
    if (idx < 64 * 320) {
        int i = idx / 320, col = idx % 320;
        float v;
        if (col < 64) {
            v = Wq[i * 64 + col];
        } else {
            int j = col - 64, set = j >> 6, l = j & 63, h = l >> 3, lc = l & 7;
            const float* Win = (set < 2) ? Wk : Wm;
            const float* T = (set == 0) ? Watt0 : (set == 1) ? Watt1 : (set == 2) ? Wmsg0 : Wmsg1;
            float scale = (set == 0) ? prior0[h] * RSQRT_C_F
                        : (set == 1) ? prior1[h] * RSQRT_C_F : 1.f;
            float acc = 0.f;
            #pragma unroll
            for (int c = 0; c < 8; c++) acc += Win[i * 64 + h * 8 + c] * T[h * 64 + c * 8 + lc];
            v = acc * scale;
        }
        Wbig[idx] = v;
    } else if (idx < 64 * 320 + 320) {
        int col = idx - 64 * 320;
        float v;
        if (col < 64) {
            v = bq[col];
        } else {
            int j = col - 64, set = j >> 6, l = j & 63, h = l >> 3, lc = l & 7;
            const float* bin = (set < 2) ? bk : bm;
            const float* T = (set == 0) ? Watt0 : (set == 1) ? Watt1 : (set == 2) ? Wmsg0 : Wmsg1;
            float scale = (set == 0) ? prior0[h] * RSQRT_C_F
                        : (set == 1) ? prior1[h] * RSQRT_C_F : 1.f;
            float acc = 0.f;
            #pragma unroll
            for (int c = 0; c < 8; c++) acc += bin[h * 8 + c] * T[h * 64 + c * 8 + lc];
            v = acc * scale;
        }
        bbig[col] = v;
    }
}

// ---------------------------------------------------------------------------
// prep2 (gridded): pack Wbig -> Wpack (40 frags) and Wa -> Wapack (8 frags).
// ---------------------------------------------------------------------------
__global__ void prep2_kernel(const float* __restrict__ Wbig, const float* __restrict__ Wa,
                             unsigned short* __restrict__ Wpack,
                             unsigned short* __restrict__ Wapack) {
    int p = blockIdx.x * TPB + threadIdx.x;
    bool isWa = (p >= 40 * 64);
    if (p >= 48 * 64) return;
    int pl = isWa ? p - 40 * 64 : p;
    int lane = pl & 63, ctkt = pl >> 6;
    int ct = ctkt >> 1, kt = ctkt & 1;
    int kbase = kt * 32 + (lane >> 4) * 8;
    int col = ct * 16 + (lane & 15);
    const float* W = isWa ? Wa : Wbig;
    const int stride = isWa ? 64 : 320;
    unsigned short h[8];
    #pragma unroll
    for (int j = 0; j < 8; j++) h[j] = f2bf(W[(size_t)(kbase + j) * stride + col]);
    uint4 pk;
    pk.x = (unsigned)h[0] | ((unsigned)h[1] << 16);
    pk.y = (unsigned)h[2] | ((unsigned)h[3] << 16);
    pk.z = (unsigned)h[4] | ((unsigned)h[5] << 16);
    pk.w = (unsigned)h[6] | ((unsigned)h[7] << 16);
    unsigned short* dst = isWa ? Wapack : Wpack;
    *(uint4*)&dst[(size_t)pl * 8] = pk;
}

// hist with 8-way sub-counters + per-edge rank output
__global__ void hist_kernel(const int* __restrict__ dst0, const int* __restrict__ dst1,
                            int* __restrict__ sub, int* __restrict__ rank,
                            int E0, int Etot, int N) {
    int e = blockIdx.x * TPB + threadIdx.x;
    if (e >= Etot) return;
    int d = (e < E0) ? dst0[e] : dst1[e - E0];
    d = min(max(d, 0), N - 1);
    rank[e] = atomicAdd(&sub[(blockIdx.x & 7) * N + d], 1);
}

// ---- scan1 (sumsub fused): reads sub counts, writes exclusive bases + offsets ----
__global__ void scan1(int* __restrict__ sub, int* __restrict__ offsets,
                      int* __restrict__ blocksums, int n) {
    __shared__ int sums[TPB];
    int b = blockIdx.x, t = threadIdx.x;
    int base = b * 1024 + t * 4;
    int cnt[4];
    #pragma unroll
    for (int i = 0; i < 4; i++) {
        int d = base + i;
        int s = 0;
        if (d < n) {
            #pragma unroll
            for (int bb = 0; bb < 8; bb++) {
                int v = sub[bb * n + d];
                sub[bb * n + d] = s;     // exclusive prefix base
                s += v;
            }
        }
        cnt[i] = s;
    }
    int local = cnt[0] + cnt[1] + cnt[2] + cnt[3];
    sums[t] = local;
    __syncthreads();
    for (int off = 1; off < TPB; off <<= 1) {
        int add = (t >= off) ? sums[t - off] : 0;
        __syncthreads();
        sums[t] += add;
        __syncthreads();
    }
    int excl = sums[t] - local;
    if (base + 0 < n) offsets[base + 0] = excl;
    if (base + 1 < n) offsets[base + 1] = excl + cnt[0];
    if (base + 2 < n) offsets[base + 2] = excl + cnt[0] + cnt[1];
    if (base + 3 < n) offsets[base + 3] = excl + cnt[0] + cnt[1] + cnt[2];
    if (t == TPB - 1) blocksums[b] = sums[TPB - 1];
}

__global__ void scan2(int* __restrict__ blocksums, int nb) {  // nb <= 256
    __shared__ int s[TPB];
    int t = threadIdx.x;
    int v = (t < nb) ? blocksums[t] : 0;
    s[t] = v;
    __syncthreads();
    for (int off = 1; off < TPB; off <<= 1) {
        int add = (t >= off) ? s[t - off] : 0;
        __syncthreads();
        s[t] += add;
        __syncthreads();
    }
    if (t < nb) blocksums[t] = s[t] - v;  // exclusive
}

// scan3 + fused addoff: finalize offsets AND fold them into the 8 sub bases
__global__ void scan3(int* __restrict__ offsets, const int* __restrict__ blocksums,
                      int* __restrict__ sub, int n, int Etot) {
    int i = blockIdx.x * TPB + threadIdx.x;
    if (i < n) {
        int v = offsets[i] + blocksums[i >> 10];
        offsets[i] = v;
        #pragma unroll
        for (int b = 0; b < 8; b++) sub[b * n + i] += v;
    }
    if (i == n) offsets[n] = Etot;
}

// scatter WITHOUT atomics: pos = sub_abs[(e>>8)&7][d] + rank[e]
__global__ void scatter_kernel(const int* __restrict__ src0, const int* __restrict__ dst0,
                               const int* __restrict__ src1, const int* __restrict__ dst1,
                               const int* __restrict__ sub,
                               const int* __restrict__ rank, unsigned* __restrict__ records,
                               int E0, int Etot, int N) {
    int e = blockIdx.x * TPB + threadIdx.x;
    if (e >= Etot) return;
    int s, d, setbit;
    if (e < E0) { s = src0[e]; d = dst0[e]; setbit = 0; }
    else        { s = src1[e - E0]; d = dst1[e - E0]; setbit = 1; }
    d = min(max(d, 0), N - 1);
    int sb = (e >> 8) & 7;   // must match hist's blockIdx&7 (TPB=256)
    int pos = sub[sb * N + d] + rank[e];
    pos = min(max(pos, 0), Etot - 1);
    records[pos] = (unsigned)s | ((unsigned)setbit << 24);
}

// ---------------------------------------------------------------------------
// MFMA projection: [N,64] x [64,320] -> q (bf16) + km (fp8 e4m3).
// kmbuf8 layout [N][256] bytes: cm = col-64 -> k0(0-63) k1(64-127) m0(128-191)
// m1(192-255); within a plane: h*8+c. ct-tile writes 16 consecutive bytes.
// ---------------------------------------------------------------------------
__global__ __launch_bounds__(TPB) void proj_mfma(const float* __restrict__ x,
                                                 const unsigned short* __restrict__ Wpack,
                                                 const float* __restrict__ bbig,
                                                 unsigned short* __restrict__ qbuf,
                                                 unsigned char* __restrict__ kmbuf8,
                                                 int N) {
    const int lane = threadIdx.x & 63;
    const int wv = threadIdx.x >> 6;
    const int rowbase = blockIdx.x * 64 + wv * 16;
    const int arow = min(rowbase + (lane & 15), N - 1);
    const int kbase = (lane >> 4) * 8;

    bf16x8 afrag[2];
    #pragma unroll
    for (int kt = 0; kt < 2; kt++) {
        const float* xp = x + (size_t)arow * 64 + kt * 32 + kbase;
        float4 v0 = *(const float4*)xp;
        float4 v1 = *(const float4*)(xp + 4);
        bf16x8 a;
        a[0] = (short)f2bf(v0.x); a[1] = (short)f2bf(v0.y);
        a[2] = (short)f2bf(v0.z); a[3] = (short)f2bf(v0.w);
        a[4] = (short)f2bf(v1.x); a[5] = (short)f2bf(v1.y);
        a[6] = (short)f2bf(v1.z); a[7] = (short)f2bf(v1.w);
        afrag[kt] = a;
    }

    const int colq = lane & 15;
    const int rgrp = (lane >> 4) * 4;

    for (int ct = 0; ct < 20; ct++) {
        bf16x8 b0 = *(const bf16x8*)(Wpack + ((size_t)(ct * 2 + 0) * 64 + lane) * 8);
        bf16x8 b1 = *(const bf16x8*)(Wpack + ((size_t)(ct * 2 + 1) * 64 + lane) * 8);
        f32x4 acc = {0.f, 0.f, 0.f, 0.f};
        acc = __builtin_amdgcn_mfma_f32_16x16x32_bf16(afrag[0], b0, acc, 0, 0, 0);
        acc = __builtin_amdgcn_mfma_f32_16x16x32_bf16(afrag[1], b1, acc, 0, 0, 0);
        const int col = ct * 16 + colq;
        const float bv = bbig[col];
        if (ct < 4) {
            #pragma unroll
            for (int r = 0; r < 4; r++) {
                int row = rowbase + rgrp + r;
                if (row < N) qbuf[(size_t)row * 64 + col] = f2bf(acc[r] + bv);
            }
        } else {
            const int cm = col - 64;   // 0..255, consecutive across lanes
            #pragma unroll
            for (int r = 0; r < 4; r++) {
                int row = rowbase + rgrp + r;
                if (row < N) kmbuf8[(size_t)row * 256 + cm] = enc8(acc[r] + bv);
            }
        }
    }
}

// ---------------------------------------------------------------------------
// Pool (fp8 gathers): one 8-lane group per receiver (wave = 8 receivers).
// lane = (g, j): g = lane>>3 receiver slot, j = lane&7 head. Fully lane-local;
// per edge the 8 lanes read ONE 64B k-line + ONE 64B m-line (half of bf16).
// No online max (scores O(0.1) by construction; fminf(s,60) guards; softmax
// shift-invariance => matches reference). Unroll x2 for load ILP.
// ---------------------------------------------------------------------------
__global__ __launch_bounds__(TPB) void pool_kernel(const unsigned short* __restrict__ qbuf,
                                                   const unsigned char* __restrict__ kmbuf8,
                                                   const unsigned* __restrict__ records,
                                                   const int* __restrict__ offsets,
                                                   unsigned short* __restrict__ pooledN,
                                                   int N) {
    const int lane = threadIdx.x & 63;
    const int j = lane & 7;
    const int r = ((blockIdx.x * TPB + threadIdx.x) >> 6) * 8 + (lane >> 3);
    if (r >= N) return;
    const int beg = offsets[r], end = offsets[r + 1];

    uint4 qv = *(const uint4*)(qbuf + (size_t)r * 64 + (j << 3));
    float qa0 = loF(qv.x), qa1 = hiF(qv.x), qa2 = loF(qv.y), qa3 = hiF(qv.y);
    float qa4 = loF(qv.z), qa5 = hiF(qv.z), qa6 = loF(qv.w), qa7 = hiF(qv.w);

    float d_run = 0.f;
    float p0 = 0.f, p1 = 0.f, p2 = 0.f, p3 = 0.f, p4 = 0.f, p5 = 0.f, p6 = 0.f, p7 = 0.f;

#define EDGE(T) {                                                              \
        unsigned rec = records[T];                                             \
        size_t base = ((size_t)(rec & 0xFFFFFFu) << 8) + (((rec >> 24) & 1u) << 6) + (j << 3); \
        uint2 kv = *(const uint2*)(kmbuf8 + base);                             \
        uint2 mv = *(const uint2*)(kmbuf8 + base + 128);                       \
        float kf[8], mf[8];                                                    \
        dec8x8(kv, kf); dec8x8(mv, mf);                                        \
        float s = kf[0] * qa0 + kf[1] * qa1 + kf[2] * qa2 + kf[3] * qa3        \
                + kf[4] * qa4 + kf[5] * qa5 + kf[6] * qa6 + kf[7] * qa7;       \
        float c = __expf(fminf(s, 60.f));                                      \
        d_run += c;                                                            \
        p0 += c * mf[0]; p1 += c * mf[1]; p2 += c * mf[2]; p3 += c * mf[3];    \
        p4 += c * mf[4]; p5 += c * mf[5]; p6 += c * mf[6]; p7 += c * mf[7];    \
    }

    int t = beg;
    for (; t + 1 < end; t += 2) { EDGE(t); EDGE(t + 1); }
    if (t < end) EDGE(t);
#undef EDGE

    const float inv = (end > beg) ? 1.f / d_run : 0.f;
    uint4 ov;
    ov.x = (unsigned)f2bf(p0 * inv) | ((unsigned)f2bf(p1 * inv) << 16);
    ov.y = (unsigned)f2bf(p2 * inv) | ((unsigned)f2bf(p3 * inv) << 16);
    ov.z = (unsigned)f2bf(p4 * inv) | ((unsigned)f2bf(p5 * inv) << 16);
    ov.w = (unsigned)f2bf(p6 * inv) | ((unsigned)f2bf(p7 * inv) << 16);
    *(uint4*)(pooledN + (size_t)r * 64 + (j << 3)) = ov;
}

// ---------------------------------------------------------------------------
// MFMA final: out = LN( sc*(gelu(pooledN) @ Wa + ba) + (1-sc)*x ).
// ---------------------------------------------------------------------------
__global__ __launch_bounds__(TPB) void final_mfma(const float* __restrict__ x,
                                                  const unsigned short* __restrict__ pooledN,
                                                  const unsigned short* __restrict__ Wapack,
                                                  const float* __restrict__ ba,
                                                  const float* __restrict__ skipw,
                                                  const float* __restrict__ gamma,
                                                  const float* __restrict__ beta,
                                                  float* __restrict__ out, int N) {
    const int lane = threadIdx.x & 63;
    const int wv = threadIdx.x >> 6;
    const int rowbase = blockIdx.x * 64 + wv * 16;
    const int arow = min(rowbase + (lane & 15), N - 1);
    const int kbase = (lane >> 4) * 8;
    const float sc = 1.f / (1.f + __expf(-skipw[0]));

    bf16x8 afrag[2];
    #pragma unroll
    for (int kt = 0; kt < 2; kt++) {
        uint4 pv = *(const uint4*)(pooledN + (size_t)arow * 64 + kt * 32 + kbase);
        float g[8];
        g[0] = loF(pv.x); g[1] = bf2f((unsigned short)(pv.x >> 16));
        g[2] = loF(pv.y); g[3] = bf2f((unsigned short)(pv.y >> 16));
        g[4] = loF(pv.z); g[5] = bf2f((unsigned short)(pv.z >> 16));
        g[6] = loF(pv.w); g[7] = bf2f((unsigned short)(pv.w >> 16));
        bf16x8 a;
        #pragma unroll
        for (int i = 0; i < 8; i++) {
            float gg = 0.5f * g[i] * (1.f + erff(g[i] * 0.70710678118654752f));
            a[i] = (short)f2bf(gg);
        }
        afrag[kt] = a;
    }

    const int colq = lane & 15;
    const int rgrp = (lane >> 4) * 4;

    float o[4][4];   // [ct][r] post-skip values
    #pragma unroll
    for (int ct = 0; ct < 4; ct++) {
        bf16x8 b0 = *(const bf16x8*)(Wapack + ((size_t)(ct * 2 + 0) * 64 + lane) * 8);
        bf16x8 b1 = *(const bf16x8*)(Wapack + ((size_t)(ct * 2 + 1) * 64 + lane) * 8);
        f32x4 acc = {0.f, 0.f, 0.f, 0.f};
        acc = __builtin_amdgcn_mfma_f32_16x16x32_bf16(afrag[0], b0, acc, 0, 0, 0);
        acc = __builtin_amdgcn_mfma_f32_16x16x32_bf16(afrag[1], b1, acc, 0, 0, 0);
        const int col = ct * 16 + colq;
        const float bav = ba[col];
        #pragma unroll
        for (int r = 0; r < 4; r++) {
            int row = min(rowbase + rgrp + r, N - 1);
            float xv = x[(size_t)row * 64 + col];
            o[ct][r] = sc * (acc[r] + bav) + (1.f - sc) * xv;
        }
    }

    #pragma unroll
    for (int r = 0; r < 4; r++) {
        float s1 = o[0][r] + o[1][r] + o[2][r] + o[3][r];
        float s2 = o[0][r] * o[0][r] + o[1][r] * o[1][r]
                 + o[2][r] * o[2][r] + o[3][r] * o[3][r];
        #pragma unroll
        for (int off = 1; off <= 8; off <<= 1) {
            s1 += __shfl_xor(s1, off, 64);
            s2 += __shfl_xor(s2, off, 64);
        }
        float mu = s1 * (1.f / 64.f);
        float var = s2 * (1.f / 64.f) - mu * mu;
        float rs = rsqrtf(var + 1e-3f);
        const int row = rowbase + rgrp + r;
        if (row < N) {
            #pragma unroll
            for (int ct = 0; ct < 4; ct++) {
                const int col = ct * 16 + colq;
                out[(size_t)row * 64 + col] = gamma[col] * (o[ct][r] - mu) * rs + beta[col];
            }
        }
    }
}

extern "C" void kernel_launch(void* const* d_in, const int* in_sizes, int n_in,
                              void* d_out, int out_size, void* d_ws, size_t ws_size,
                              hipStream_t stream) {
    const float* x      = (const float*)d_in[0];
    const int*   src0   = (const int*)d_in[1];
    const int*   dst0   = (const int*)d_in[2];
    const int*   src1   = (const int*)d_in[3];
    const int*   dst1   = (const int*)d_in[4];
    const float* Wk     = (const float*)d_in[5];
    const float* bk     = (const float*)d_in[6];
    const float* Wm     = (const float*)d_in[7];
    const float* bm     = (const float*)d_in[8];
    const float* Wq     = (const float*)d_in[9];
    const float* bq     = (const float*)d_in[10];
    const float* Wa     = (const float*)d_in[11];
    const float* ba     = (const float*)d_in[12];
    const float* Watt0  = (const float*)d_in[13];
    const float* Wmsg0  = (const float*)d_in[14];
    const float* prior0 = (const float*)d_in[15];
    const float* Watt1  = (const float*)d_in[16];
    const float* Wmsg1  = (const float*)d_in[17];
    const float* prior1 = (const float*)d_in[18];
    const float* skipw  = (const float*)d_in[19];
    const float* gamma  = (const float*)d_in[20];
    const float* beta   = (const float*)d_in[21];

    const int N  = in_sizes[0] / 64;
    const int E0 = in_sizes[1];
    const int E1 = in_sizes[3];
    const int Etot = E0 + E1;

    // workspace layout
    float* ws       = (float*)d_ws;
    float* Wbig     = ws;                                   // 64*320 f32
    float* bbig     = Wbig + 64 * 320;                      // 320 f32
    unsigned short* Wpack  = (unsigned short*)(bbig + 320); // 40*64*8 bf16 (40 KB)
    unsigned short* Wapack = Wpack + 40 * 64 * 8;           // 8*64*8 bf16 (8 KB)
    unsigned short* qbuf   = Wapack + 8 * 64 * 8;           // N*64 bf16
    unsigned short* pooledN = qbuf + (size_t)N * 64;        // N*64 bf16
    unsigned char* kmbuf8  = (unsigned char*)(pooledN + (size_t)N * 64);  // N*256 fp8
    int* sub        = (int*)(kmbuf8 + (size_t)N * 256);     // 8*N (counts -> abs bases)
    int* offsets    = sub + (size_t)8 * N;                  // N+1
    int* blocksums  = offsets + N + 1;                      // <=512
    int* rank       = blocksums + 512;                      // Etot
    unsigned* records = (unsigned*)(rank + Etot);           // Etot

    const int nb1 = (N + 1023) / 1024;
    const int gE = (Etot + TPB - 1) / TPB;

    prep1_kernel<<<(64 * 320 + 320 + TPB - 1) / TPB, TPB, 0, stream>>>(
        Wq, bq, Wk, bk, Wm, bm, Watt0, prior0, Watt1, prior1, Wmsg0, Wmsg1, Wbig, bbig);
    hipMemsetAsync(sub, 0, (size_t)8 * N * sizeof(int), stream);
    prep2_kernel<<<(48 * 64 + TPB - 1) / TPB, TPB, 0, stream>>>(Wbig, Wa, Wpack, Wapack);

    proj_mfma<<<(N + 63) / 64, TPB, 0, stream>>>(x, Wpack, bbig, qbuf, kmbuf8, N);

    hist_kernel<<<gE, TPB, 0, stream>>>(dst0, dst1, sub, rank, E0, Etot, N);

    scan1<<<nb1, TPB, 0, stream>>>(sub, offsets, blocksums, N);
    scan2<<<1, TPB, 0, stream>>>(blocksums, nb1);
    scan3<<<(N + 1 + TPB - 1) / TPB, TPB, 0, stream>>>(offsets, blocksums, sub, N, Etot);

    scatter_kernel<<<gE, TPB, 0, stream>>>(src0, dst0, src1, dst1, sub,
                                           rank, records, E0, Etot, N);

    pool_kernel<<<((size_t)N * 8 + TPB - 1) / TPB, TPB, 0, stream>>>(qbuf, kmbuf8, records,
                                                                     offsets, pooledN, N);

    final_mfma<<<(N + 63) / 64, TPB, 0, stream>>>(x, pooledN, Wapack, ba, skipw,
                                                  gamma, beta, (float*)d_out, N);
}